// Round 15
// baseline (419.509 us; speedup 1.0000x reference)
//
#include <hip/hip_runtime.h>
#include <stdint.h>

// GraphConvLayer: out[n,:] = W[type[n]] @ (A @ x)[n,:]
// N=16384, D=128, T=8.  A is 1 GiB f32 read exactly once -> HBM floor ~163us.
// Round 15 = Round 13 (best, 310us) halved per-block + SPLITK=2:
//   BK=64, LDS 64KB/block -> 2 independent 8-wave blocks per CU, phase-
//   shifted so one block's LDS/compute burst overlaps the other's HBM wait
//   (R13's single 131KB block serialized them in barrier lockstep).
//   Same DMA->LDS staging, counted vmcnt(4) (never 0 until tail), same
//   XOR swizzle discipline rescaled to 256B (A) / 128B (X) rows.
// Partials f32 -> g_part; R9's verified f32 epilogue applies W[type].

#define N_NODES 16384
#define DIM     128
#define NTYPES  8
#define BM      64
#define BK      64
#define SPLITK  2
#define KSLICE  (N_NODES / SPLITK)   // 8192
#define NPH     (KSLICE / BK)        // 128 phases per block

typedef float  f32x4  __attribute__((ext_vector_type(4)));
typedef __bf16 bf16x8 __attribute__((ext_vector_type(8)));

__device__ __attribute__((aligned(16))) unsigned short g_xT[DIM * N_NODES];    // [d][n], 4 MiB bf16
__device__ __attribute__((aligned(16))) float g_part[SPLITK * N_NODES * DIM];  // 16 MiB f32 partials

__device__ __forceinline__ unsigned int f2b(float f) {
    unsigned int u = __float_as_uint(f);
    u += 0x7FFFu + ((u >> 16) & 1u);   // round-to-nearest-even
    return u >> 16;
}

__device__ __forceinline__ bf16x8 cvt8(const f32x4 lo, const f32x4 hi) {
    bf16x8 r;
    r[0] = (__bf16)lo[0]; r[1] = (__bf16)lo[1]; r[2] = (__bf16)lo[2]; r[3] = (__bf16)lo[3];
    r[4] = (__bf16)hi[0]; r[5] = (__bf16)hi[1]; r[6] = (__bf16)hi[2]; r[7] = (__bf16)hi[3];
    return r;
}

// ---------------- prep: x -> bf16 transposed [d][n] ----------------

__global__ void prep_xT(const float* __restrict__ x) {
    int n = blockIdx.x * 256 + threadIdx.x;          // 64 blocks x 256
    const float* row = x + (size_t)n * DIM;
#pragma unroll
    for (int d0 = 0; d0 < DIM; d0 += 4) {
        float4 v = *(const float4*)(row + d0);
        g_xT[(d0 + 0) * N_NODES + n] = (unsigned short)f2b(v.x);
        g_xT[(d0 + 1) * N_NODES + n] = (unsigned short)f2b(v.y);
        g_xT[(d0 + 2) * N_NODES + n] = (unsigned short)f2b(v.z);
        g_xT[(d0 + 3) * N_NODES + n] = (unsigned short)f2b(v.w);
    }
}

// ---------------- main GEMM kernel (split-K, DMA staging) ----------------

#define ABYTES 16384   // A tile: 64 rows x 256B (f32; 16 x 16B chunks/row)
#define XBYTES 16384   // X tile: 128 d-rows x 128B (bf16; 8 x 16B chunks/row)

#define GLOAD16(g, l) __builtin_amdgcn_global_load_lds(                         \
    (const __attribute__((address_space(1))) unsigned int*)(g),                 \
    (__attribute__((address_space(3))) unsigned int*)(l), 16, 0, 0)

// 4 DMA calls per wave per tile: A j=0/1 (32 rows each), X j=0/1 (64 d each)
#define DMA4(Ab, Xb) do {                          \
    GLOAD16(gA0, (Ab) + wq);                       \
    GLOAD16(gA1, (Ab) + 8192 + wq);                \
    GLOAD16(gX0, (Xb) + wq);                       \
    GLOAD16(gX1, (Xb) + 8192 + wq);                \
    gA0 += BK; gA1 += BK; gX0 += BK; gX1 += BK;    \
} while (0)

// one k-substep (32 k): A frag (2 f32x4 + cvt) x 4 X frags -> 4 MFMA
#define KSUB(Ab, Xb, aoE, aoO, xk) do {                                         \
    f32x4 _e = *(const f32x4*)((Ab) + (aoE));                                   \
    f32x4 _o = *(const f32x4*)((Ab) + (aoO));                                   \
    bf16x8 _a = cvt8(_e, _o);                                                   \
    bf16x8 _b0 = *(const bf16x8*)((Xb) + xbase + (xk));                         \
    bf16x8 _b1 = *(const bf16x8*)((Xb) + xbase + (xk) + 2048);                  \
    bf16x8 _b2 = *(const bf16x8*)((Xb) + xbase + (xk) + 4096);                  \
    bf16x8 _b3 = *(const bf16x8*)((Xb) + xbase + (xk) + 6144);                  \
    acc0 = __builtin_amdgcn_mfma_f32_16x16x32_bf16(_a, _b0, acc0, 0, 0, 0);     \
    acc1 = __builtin_amdgcn_mfma_f32_16x16x32_bf16(_a, _b1, acc1, 0, 0, 0);     \
    acc2 = __builtin_amdgcn_mfma_f32_16x16x32_bf16(_a, _b2, acc2, 0, 0, 0);     \
    acc3 = __builtin_amdgcn_mfma_f32_16x16x32_bf16(_a, _b3, acc3, 0, 0, 0);     \
} while (0)

#define COMPUTE(Ab, Xb) do {                 \
    KSUB(Ab, Xb, aoE0, aoO0, xk0);           \
    KSUB(Ab, Xb, aoE1, aoO1, xk1);           \
} while (0)

// phase: vmcnt(4) [tile t's 4 done, t+1's 4 in flight] -> barrier -> compute t
// -> barrier (all waves done reading) -> issue t+2 into the freed buffer.
#define PHASE_I(Ac, Xc) do {                                 \
    asm volatile("s_waitcnt vmcnt(4)" ::: "memory");         \
    __builtin_amdgcn_s_barrier();                            \
    COMPUTE(Ac, Xc);                                         \
    asm volatile("s_barrier" ::: "memory");                  \
    DMA4(Ac, Xc);                                            \
} while (0)

__global__ __launch_bounds__(512, 4) void gconv_main(const float* __restrict__ adj)
{
    __shared__ __align__(16) unsigned char lds[2 * (ABYTES + XBYTES)]; // 65536 B
    unsigned char* Ab0 = lds;
    unsigned char* Ab1 = lds + ABYTES;
    unsigned char* Xb0 = lds + 2 * ABYTES;
    unsigned char* Xb1 = Xb0 + XBYTES;

    const int tid  = threadIdx.x;
    const int w    = tid >> 6;                    // 0..7
    const int l    = tid & 63;
    const int ks   = blockIdx.x & 1;              // k-slice
    const int m0   = (blockIdx.x >> 1) * BM;      // row block
    const int kb   = ks * KSLICE;

    const int mrow = (w & 3) * 16;      // wave's 16 output rows (of 64)
    const int ncol = (w >> 2) * 64;     // wave's 64 output cols (of 128)

    f32x4 acc0 = {}, acc1 = {}, acc2 = {}, acc3 = {};

    // ---- DMA source pointers (pre-swizzled; linear LDS dest, m173/T2) ----
    // A call j: LDS row = j*32 + 4w + (l>>4) (256B rows), phys chunk = l&15,
    //           source logical chunk = (l&15) ^ (row&7)
    const int arw = 4 * w + (l >> 4);
    const float* gA0 = adj + (size_t)(m0 + arw) * N_NODES + kb
                     + (((l & 15) ^ (arw & 7)) << 2);
    const float* gA1 = gA0 + (size_t)32 * N_NODES;
    // X call j: LDS d-row = j*64 + 8w + (l>>3) (128B rows), phys chunk = l&7,
    //           source logical chunk = (l&7) ^ (d&7)
    const int xdw = 8 * w + (l >> 3);
    const unsigned short* gX0 = g_xT + (size_t)xdw * N_NODES + kb
                              + (((l & 7) ^ (xdw & 7)) << 3);
    const unsigned short* gX1 = gX0 + (size_t)64 * N_NODES;
    const int wq = w << 10;             // wave's 1KB slot within each 8KB round

    // ---- compute-side byte offsets (XOR matches the source swizzle) ----
    // A: row r = mrow+(l&15), r&7 = l&7; ksub kc: logical chunks kc*8+2h, +1
    const int h    = l >> 4;
    const int r    = mrow + (l & 15);
    const int aoE0 = r * 256 + (((0 + 2 * h)     ^ (l & 7)) << 4);
    const int aoO0 = r * 256 + (((0 + 2 * h + 1) ^ (l & 7)) << 4);
    const int aoE1 = r * 256 + (((8 + 2 * h)     ^ (l & 7)) << 4);
    const int aoO1 = r * 256 + (((8 + 2 * h + 1) ^ (l & 7)) << 4);
    // X: d = ncol + nt*16 + (l&15), d&7 = l&7; ksub kc: logical chunk kc*4+h
    const int xbase = (ncol + (l & 15)) * 128;            // + nt*2048 per frag
    const int xk0   = ((0 + h) ^ (l & 7)) << 4;
    const int xk1   = ((4 + h) ^ (l & 7)) << 4;

    // ---- prologue: tiles 0 and 1 in flight (8 calls/wave outstanding) ----
    DMA4(Ab0, Xb0);
    DMA4(Ab1, Xb1);

    // ---- 128 phases: 63 x 2 issuing (t=0..125) + 2 tail ----
    for (int i = 0; i < 63; ++i) {
        PHASE_I(Ab0, Xb0);              // t even: compute buf0, issue t+2 -> buf0
        PHASE_I(Ab1, Xb1);              // t odd
    }
    asm volatile("s_waitcnt vmcnt(4)" ::: "memory");   // t=126
    __builtin_amdgcn_s_barrier();
    COMPUTE(Ab0, Xb0);
    asm volatile("s_waitcnt vmcnt(0)" ::: "memory");   // t=127
    __builtin_amdgcn_s_barrier();
    COMPUTE(Ab1, Xb1);

    // ---- partial store: f32 accumulators -> g_part[ks] ----
    // C/D layout: col = lane&15, row = (lane>>4)*4 + reg
    float* pp = g_part + (size_t)ks * (N_NODES * DIM)
              + (size_t)(m0 + mrow + (l >> 4) * 4) * DIM + ncol + (l & 15);
#define STACC(nt) do {                          \
    pp[0 * DIM + (nt) * 16] = acc##nt[0];       \
    pp[1 * DIM + (nt) * 16] = acc##nt[1];       \
    pp[2 * DIM + (nt) * 16] = acc##nt[2];       \
    pp[3 * DIM + (nt) * 16] = acc##nt[3];       \
} while (0)
    STACC(0); STACC(1); STACC(2); STACC(3);
#undef STACC
}

// ---------------- epilogue: reduce partials + W[type] projection (f32) ----------------

__global__ __launch_bounds__(256) void gconv_epi(
    const float* __restrict__ wt,
    const int* __restrict__ types,
    float* __restrict__ out)
{
    __shared__ __align__(16) float agg[BM * 132];   // 33792 B

    const int tid  = threadIdx.x;
    const int w    = tid >> 6;
    const int lane = tid & 63;
    const int m0   = blockIdx.x * BM;

    // phase 1: agg[node][d] = part0 + part1
#pragma unroll
    for (int j = 0; j < 8; ++j) {
        const int f    = tid + j * 256;        // float4 index within 64x128 tile
        const int node = f >> 5;
        const int d4   = (f & 31) * 4;
        const float* p = g_part + (size_t)(m0 + node) * DIM + d4;
        float4 s0 = *(const float4*)(p);
        float4 s1 = *(const float4*)(p + (size_t)N_NODES * DIM);
        float4 s; s.x = s0.x + s1.x; s.y = s0.y + s1.y;
        s.z = s0.z + s1.z; s.w = s0.w + s1.w;
        *(float4*)&agg[node * 132 + d4] = s;
    }
    __syncthreads();

    // phase 2: out[n] = W[type[n]] @ agg[n]  (f32, lane -> 2 output features)
    const int rbase = w * 16;   // 16 nodes per wave
    for (int rr = 0; rr < 16; ++rr) {
        const int rw = rbase + rr;
        const int nn = m0 + rw;
        const int ty = types[nn];                       // wave-uniform
        const float* Wt = wt + (size_t)ty * DIM * DIM;
        const int o0 = lane * 2;
        const float* aggRow = agg + rw * 132;
        float s0 = 0.f, s1 = 0.f;
#pragma unroll
        for (int d0 = 0; d0 < DIM; d0 += 8) {
            float4 ga = *(const float4*)(aggRow + d0);
            float4 gb = *(const float4*)(aggRow + d0 + 4);
            float4 wa0 = *(const float4*)(Wt + (size_t)o0 * DIM + d0);
            float4 wa1 = *(const float4*)(Wt + (size_t)o0 * DIM + d0 + 4);
            float4 wb0 = *(const float4*)(Wt + (size_t)(o0 + 1) * DIM + d0);
            float4 wb1 = *(const float4*)(Wt + (size_t)(o0 + 1) * DIM + d0 + 4);
            s0 += ga.x * wa0.x + ga.y * wa0.y + ga.z * wa0.z + ga.w * wa0.w;
            s0 += gb.x * wa1.x + gb.y * wa1.y + gb.z * wa1.z + gb.w * wa1.w;
            s1 += ga.x * wb0.x + ga.y * wb0.y + ga.z * wb0.z + ga.w * wb0.w;
            s1 += gb.x * wb1.x + gb.y * wb1.y + gb.z * wb1.z + gb.w * wb1.w;
        }
        float2 res; res.x = s0; res.y = s1;
        *(float2*)(out + (size_t)nn * DIM + o0) = res;
    }
}

// ---------------- launch ----------------

extern "C" void kernel_launch(void* const* d_in, const int* in_sizes, int n_in,
                              void* d_out, int out_size, void* d_ws, size_t ws_size,
                              hipStream_t stream) {
    const float* x     = (const float*)d_in[0];
    const int*   types = (const int*)d_in[1];
    const float* adj   = (const float*)d_in[2];
    const float* wt    = (const float*)d_in[3];
    float* out = (float*)d_out;

    hipLaunchKernelGGL(prep_xT, dim3(64), dim3(256), 0, stream, x);
    hipLaunchKernelGGL(gconv_main, dim3((N_NODES / BM) * SPLITK), dim3(512), 0, stream, adj);
    hipLaunchKernelGGL(gconv_epi, dim3(N_NODES / BM), dim3(256), 0, stream, wt, types, out);
}